// Round 2
// baseline (839.300 us; speedup 1.0000x reference)
//
#include <hip/hip_runtime.h>
#include <math.h>

#define HDIM 4096
#define NEXP 64
#define NTOK 16384
#define MB   64     // tokens per block (= lanes per wave)
#define KC   64     // k-chunk staged in LDS
#define EPW  8      // experts per wave
#define NWAVES 8    // 512 threads
#define ASTRIDE 68  // A-tile row stride (floats): 16B-aligned, even bank spread for b128

// Fused router: fp32 GEMM (logits) + softmax + top-2 + loss partials.
// 256 blocks x 512 threads. Wave w owns experts [8w,8w+8); lane = token.
// A-chunk staged in LDS token-major, then preloaded to VGPRs (ds_read_b128 x16)
// so the FMA body contains only scalar (SMEM) gate loads -> no lgkmcnt
// ds/smem mixing drains inside the hot loop.
__global__ __launch_bounds__(512) void router_main(
    const float* __restrict__ hidden,
    const float* __restrict__ gate,
    float* __restrict__ out_rw,    // [NTOK*2]
    float* __restrict__ out_sel,   // [NTOK*2] indices as floats
    float* __restrict__ psum_g,    // [64] sum of probs per expert
    float* __restrict__ cnt_g,     // [64] selection counts per expert
    float* __restrict__ zsum_g)    // [1] sum of lse^2
{
    __shared__ float A_lds[MB * ASTRIDE];
    __shared__ float C_lds[MB * 65];
    __shared__ float rden[MB];
    __shared__ unsigned hist[NEXP];

    const int t = threadIdx.x;
    const int lane = t & 63;
    const int wave = __builtin_amdgcn_readfirstlane(t >> 6);   // SGPR
    const int m0 = blockIdx.x * MB;
    const float* __restrict__ gp = gate + (size_t)wave * EPW * HDIM;

    float acc[EPW];
#pragma unroll
    for (int j = 0; j < EPW; ++j) acc[j] = 0.f;

    const float4* __restrict__ A4 = (const float4*)hidden;
    float4 pref[2];
#pragma unroll
    for (int i = 0; i < 2; ++i) {
        int idx = t + 512 * i;              // chunk = 64 rows x 16 float4
        int m = idx >> 4, kq = idx & 15;
        pref[i] = A4[(size_t)(m0 + m) * (HDIM / 4) + kq];
    }

    for (int kc = 0; kc < HDIM / KC; ++kc) {
        // store prefetched A tile: A_lds[m][k], b128 stores
#pragma unroll
        for (int i = 0; i < 2; ++i) {
            int idx = t + 512 * i;
            int m = idx >> 4, kq = idx & 15;
            *(float4*)&A_lds[m * ASTRIDE + 4 * kq] = pref[i];
        }
        __syncthreads();
        // issue next chunk's global loads (vmcnt; overlaps FMA body)
        if (kc + 1 < HDIM / KC) {
            int cb = (kc + 1) * (KC / 4);
#pragma unroll
            for (int i = 0; i < 2; ++i) {
                int idx = t + 512 * i;
                int m = idx >> 4, kq = idx & 15;
                pref[i] = A4[(size_t)(m0 + m) * (HDIM / 4) + cb + kq];
            }
        }
        // preload this lane's 64 a-values into VGPRs (16x ds_read_b128)
        float a[KC];
#pragma unroll
        for (int j = 0; j < KC / 4; ++j) {
            float4 v = *(const float4*)&A_lds[lane * ASTRIDE + 4 * j];
            a[4 * j + 0] = v.x; a[4 * j + 1] = v.y;
            a[4 * j + 2] = v.z; a[4 * j + 3] = v.w;
        }
        // FMA body: gate via uniform float4 loads (s_load_dwordx4), no DS ops
        const size_t kb = (size_t)kc * KC;
#pragma unroll
        for (int w4 = 0; w4 < KC / 4; ++w4) {
#pragma unroll
            for (int j = 0; j < EPW; ++j) {
                float4 g = *(const float4*)&gp[(size_t)j * HDIM + kb + 4 * w4];
                acc[j] = fmaf(a[4 * w4 + 0], g.x, acc[j]);
                acc[j] = fmaf(a[4 * w4 + 1], g.y, acc[j]);
                acc[j] = fmaf(a[4 * w4 + 2], g.z, acc[j]);
                acc[j] = fmaf(a[4 * w4 + 3], g.w, acc[j]);
            }
        }
        __syncthreads();
    }

    // logits -> C_lds[token(lane)][expert]
#pragma unroll
    for (int j = 0; j < EPW; ++j)
        C_lds[lane * 65 + wave * EPW + j] = acc[j];
    if (t < NEXP) hist[t] = 0u;
    __syncthreads();

    if (wave != 0) return;   // epilogue on wave 0 only (no barriers below)

    // top-2 (strict >, ascending e => ties pick lower index, matches jax)
    float v1 = -INFINITY, v2 = -INFINITY;
    int i1 = 0, i2 = 0;
    for (int e = 0; e < NEXP; ++e) {
        float v = C_lds[lane * 65 + e];
        if (v > v1)      { v2 = v1; i2 = i1; v1 = v; i1 = e; }
        else if (v > v2) { v2 = v;  i2 = e; }
    }
    atomicAdd(&hist[i1], 1u);
    atomicAdd(&hist[i2], 1u);

    // softmax denom, z-loss, outputs
    float d = 0.f;
    for (int e = 0; e < NEXP; ++e) {
        float ev = expf(C_lds[lane * 65 + e] - v1);
        C_lds[lane * 65 + e] = ev;   // keep exp for prob-sum pass
        d += ev;
    }
    rden[lane] = 1.0f / d;
    float lse = v1 + logf(d);
    float z = lse * lse;

    float e2 = expf(v2 - v1);
    float w2 = e2 / (1.f + e2);      // p2/(p1+p2)
    float w1 = 1.f - w2;
    int tok = m0 + lane;
    out_rw[2 * tok + 0] = w1;
    out_rw[2 * tok + 1] = w2;
    out_sel[2 * tok + 0] = (float)i1;
    out_sel[2 * tok + 1] = (float)i2;

#pragma unroll
    for (int off = 32; off > 0; off >>= 1) z += __shfl_down(z, off);
    if (lane == 0) atomicAdd(zsum_g, z);

    // per-expert prob sums over this block's 64 tokens (lane = expert)
    float ps = 0.f;
    for (int m = 0; m < MB; ++m)
        ps += C_lds[m * 65 + lane] * rden[m];
    atomicAdd(&psum_g[lane], ps);
    atomicAdd(&cnt_g[lane], (float)hist[lane]);
}

// Combine per-expert partials into the scalar router loss.
__global__ void router_final(const float* __restrict__ ws, float* __restrict__ out_loss)
{
    int e = threadIdx.x;  // 64 threads
    const float inv = 1.0f / (float)NTOK;
    float p = (ws[64 + e] * inv) * (ws[e] * inv);
#pragma unroll
    for (int off = 32; off > 0; off >>= 1) p += __shfl_down(p, off);
    if (e == 0)
        out_loss[0] = 0.01f * (64.f * p) + 0.001f * (ws[128] * inv);
}

extern "C" void kernel_launch(void* const* d_in, const int* in_sizes, int n_in,
                              void* d_out, int out_size, void* d_ws, size_t ws_size,
                              hipStream_t stream) {
    const float* hidden = (const float*)d_in[0];   // [4,4096,4096] fp32
    const float* gate   = (const float*)d_in[1];   // [64,4096] fp32
    float* out = (float*)d_out;                    // 65537 floats
    float* ws  = (float*)d_ws;                     // psum[64] | cnt[64] | zsum[1]

    hipMemsetAsync(d_ws, 0, 129 * sizeof(float), stream);
    router_main<<<dim3(NTOK / MB), dim3(512), 0, stream>>>(
        hidden, gate,
        out,                 // routing weights
        out + NTOK * 2,      // selected experts (as floats)
        ws, ws + 64, ws + 128);
    router_final<<<dim3(1), dim3(64), 0, stream>>>(ws, out + NTOK * 4);
}

// Round 3
// 539.189 us; speedup vs baseline: 1.5566x; 1.5566x over previous
//
#include <hip/hip_runtime.h>
#include <math.h>

#define HDIM 4096
#define NEXP 64
#define NTOK 16384
#define MBLK 64      // tokens per block
#define TT   16      // token tile (acc rows per lane)
#define KC   256     // k-chunk: lane l owns k = 4l..4l+3
#define NCHUNK (HDIM / KC)       // 16
#define NTILE  (MBLK / TT)       // 4
#define CSTRIDE 68   // C_lds row stride (16B-aligned, conflict-spread)

// DPP-add helper: x + dpp_select(x). Masked-out rows contribute 0.
template <int CTRL, int RMASK>
__device__ __forceinline__ float dpp_add(float x) {
    int xi = __builtin_bit_cast(int, x);
    int yi = __builtin_amdgcn_update_dpp(0, xi, CTRL, RMASK, 0xF, true);
    return x + __builtin_bit_cast(float, yi);
}

// Fused router. 256 blocks x 512 threads (8 waves, 2/SIMD).
// Wave w owns experts [8w, 8w+8). Lane l owns k-slice 4l..4l+3 per 256-k chunk.
// Gate fragment lives in VGPRs (8 x float4, reloaded per chunk from global/L2);
// A staged in LDS (16 tokens x 256 k = 16 KB), ds_read_b128 per (token,lane).
__global__ __launch_bounds__(512, 2) void router_main(
    const float* __restrict__ hidden,
    const float* __restrict__ gate,
    float* __restrict__ out_rw,
    float* __restrict__ out_sel,
    float* __restrict__ psum_g,
    float* __restrict__ cnt_g,
    float* __restrict__ zsum_g)
{
    __shared__ float A_lds[TT * KC];          // 16 KB, no pad needed (dense b128)
    __shared__ float C_lds[MBLK * CSTRIDE];   // logits [token][expert]
    __shared__ float rden[MBLK];
    __shared__ unsigned hist[NEXP];

    const int t = threadIdx.x;
    const int lane = t & 63;
    const int wave = __builtin_amdgcn_readfirstlane(t >> 6);
    const int m0 = blockIdx.x * MBLK;

    const float4* __restrict__ A4 = (const float4*)hidden;   // row = 1024 float4
    const float4* __restrict__ G4 = (const float4*)gate;     // row = 1024 float4

    // ---- staging helpers: iteration it = tile*16 + chunk ----
    // thread t, round r: element e = r*512+t; m = e>>6 (token in tile), c4 = e&63
    // wave-level: m = r*8 + w (uniform), c4 = lane  -> coalesced b128, dense LDS write
    float4 pref[2];
    {
        int tb = 0, kb4 = 0;
#pragma unroll
        for (int r = 0; r < 2; ++r) {
            int m = r * 8 + wave;
            pref[r] = A4[(size_t)(m0 + tb + m) * (HDIM / 4) + kb4 + lane];
        }
    }

    for (int tile = 0; tile < NTILE; ++tile) {
        float acc[TT][8];
#pragma unroll
        for (int tt = 0; tt < TT; ++tt)
#pragma unroll
            for (int e = 0; e < 8; ++e) acc[tt][e] = 0.f;

        for (int chunk = 0; chunk < NCHUNK; ++chunk) {
            const int it = tile * NCHUNK + chunk;
            __syncthreads();   // previous chunk's A reads done
#pragma unroll
            for (int r = 0; r < 2; ++r) {
                int m = r * 8 + wave;
                *(float4*)&A_lds[m * KC + lane * 4] = pref[r];
            }
            __syncthreads();   // A tile ready
            // prefetch next iteration's A fragment (global, vmcnt)
            if (it + 1 < NTILE * NCHUNK) {
                int tb = ((it + 1) >> 4) * TT;
                int kb4 = ((it + 1) & 15) * (KC / 4);
#pragma unroll
                for (int r = 0; r < 2; ++r) {
                    int m = r * 8 + wave;
                    pref[r] = A4[(size_t)(m0 + tb + m) * (HDIM / 4) + kb4 + lane];
                }
            }
            // gate fragment for this chunk: 8 experts x 4 k-values (VGPRs)
            float4 g[8];
#pragma unroll
            for (int e = 0; e < 8; ++e)
                g[e] = G4[(size_t)(wave * 8 + e) * (HDIM / 4) + chunk * (KC / 4) + lane];
            // compute: per token 1 ds_read_b128 -> 32 FMAs
#pragma unroll
            for (int tt = 0; tt < TT; ++tt) {
                float4 a = *(const float4*)&A_lds[tt * KC + lane * 4];
#pragma unroll
                for (int e = 0; e < 8; ++e) {
                    acc[tt][e] = fmaf(a.x, g[e].x, acc[tt][e]);
                    acc[tt][e] = fmaf(a.y, g[e].y, acc[tt][e]);
                    acc[tt][e] = fmaf(a.z, g[e].z, acc[tt][e]);
                    acc[tt][e] = fmaf(a.w, g[e].w, acc[tt][e]);
                }
            }
        }

        // cross-lane K-reduction: 6 DPP adds -> total in lanes 48..63
#pragma unroll
        for (int tt = 0; tt < TT; ++tt)
#pragma unroll
            for (int e = 0; e < 8; ++e) {
                float x = acc[tt][e];
                x = dpp_add<0xB1,  0xF>(x);   // quad_perm xor1
                x = dpp_add<0x4E,  0xF>(x);   // quad_perm xor2
                x = dpp_add<0x141, 0xF>(x);   // row_half_mirror (8-sum)
                x = dpp_add<0x140, 0xF>(x);   // row_mirror (16-sum)
                x = dpp_add<0x142, 0xA>(x);   // bcast15 -> rows 1,3
                x = dpp_add<0x143, 0xC>(x);   // bcast31 -> rows 2,3
                acc[tt][e] = x;
            }
        if (lane == 48) {
#pragma unroll
            for (int tt = 0; tt < TT; ++tt) {
                *(float4*)&C_lds[(tile * TT + tt) * CSTRIDE + wave * 8 + 0] =
                    make_float4(acc[tt][0], acc[tt][1], acc[tt][2], acc[tt][3]);
                *(float4*)&C_lds[(tile * TT + tt) * CSTRIDE + wave * 8 + 4] =
                    make_float4(acc[tt][4], acc[tt][5], acc[tt][6], acc[tt][7]);
            }
        }
    }

    if (t < NEXP) hist[t] = 0u;
    __syncthreads();

    if (wave != 0) return;   // epilogue on wave 0 only

    // top-2 (strict >, ascending e => ties pick lower index, matches jax)
    float v1 = -INFINITY, v2 = -INFINITY;
    int i1 = 0, i2 = 0;
    for (int e = 0; e < NEXP; ++e) {
        float v = C_lds[lane * CSTRIDE + e];
        if (v > v1)      { v2 = v1; i2 = i1; v1 = v; i1 = e; }
        else if (v > v2) { v2 = v;  i2 = e; }
    }
    atomicAdd(&hist[i1], 1u);
    atomicAdd(&hist[i2], 1u);

    float d = 0.f;
    for (int e = 0; e < NEXP; ++e) {
        float ev = expf(C_lds[lane * CSTRIDE + e] - v1);
        C_lds[lane * CSTRIDE + e] = ev;
        d += ev;
    }
    rden[lane] = 1.0f / d;
    float lse = v1 + logf(d);
    float z = lse * lse;

    float e2 = expf(v2 - v1);
    float w2 = e2 / (1.f + e2);
    float w1 = 1.f - w2;
    int tok = m0 + lane;
    out_rw[2 * tok + 0] = w1;
    out_rw[2 * tok + 1] = w2;
    out_sel[2 * tok + 0] = (float)i1;
    out_sel[2 * tok + 1] = (float)i2;

#pragma unroll
    for (int off = 32; off > 0; off >>= 1) z += __shfl_down(z, off);
    if (lane == 0) atomicAdd(zsum_g, z);

    float ps = 0.f;
    for (int m = 0; m < MBLK; ++m)
        ps += C_lds[m * CSTRIDE + lane] * rden[m];
    atomicAdd(&psum_g[lane], ps);
    atomicAdd(&cnt_g[lane], (float)hist[lane]);
}

__global__ void router_final(const float* __restrict__ ws, float* __restrict__ out_loss)
{
    int e = threadIdx.x;  // 64 threads
    const float inv = 1.0f / (float)NTOK;
    float p = (ws[64 + e] * inv) * (ws[e] * inv);
#pragma unroll
    for (int off = 32; off > 0; off >>= 1) p += __shfl_down(p, off);
    if (e == 0)
        out_loss[0] = 0.01f * (64.f * p) + 0.001f * (ws[128] * inv);
}

extern "C" void kernel_launch(void* const* d_in, const int* in_sizes, int n_in,
                              void* d_out, int out_size, void* d_ws, size_t ws_size,
                              hipStream_t stream) {
    const float* hidden = (const float*)d_in[0];   // [4,4096,4096] fp32
    const float* gate   = (const float*)d_in[1];   // [64,4096] fp32
    float* out = (float*)d_out;                    // 65537 floats
    float* ws  = (float*)d_ws;                     // psum[64] | cnt[64] | zsum[1]

    hipMemsetAsync(d_ws, 0, 129 * sizeof(float), stream);
    router_main<<<dim3(NTOK / MBLK), dim3(512), 0, stream>>>(
        hidden, gate,
        out,                 // routing weights
        out + NTOK * 2,      // selected experts (as floats)
        ws, ws + 64, ws + 128);
    router_final<<<dim3(1), dim3(64), 0, stream>>>(ws, out + NTOK * 4);
}